// Round 2
// baseline (5361.514 us; speedup 1.0000x reference)
//
#include <hip/hip_runtime.h>
#include <hip/hip_fp16.h>

// Problem constants
#define NQ   2048      // N_LC == N_TE
#define NB   4         // batch
#define DD   256       // feature dim
#define M1   2049      // NQ + dustbin
#define STR  2064      // padded row stride (halfs), multiple of 8
#define SINK_ITERS 100
#define NWG  256       // cooperative workgroups (1 per CU)
#define NLEAF 16       // barrier fan-in leaves

typedef __attribute__((ext_vector_type(8))) short short8;
typedef __attribute__((ext_vector_type(4))) float floatx4;

__device__ __forceinline__ unsigned short f2bf(float f) {
  unsigned u = __float_as_uint(f);
  u += 0x7FFF + ((u >> 16) & 1);   // round-to-nearest-even
  return (unsigned short)(u >> 16);
}

// ---------------- fp32 -> bf16 convert ----------------
__global__ void k_cvt(const float* __restrict__ src, unsigned short* __restrict__ dst, int n) {
  int i = blockIdx.x * blockDim.x + threadIdx.x;
  if (i < n) dst[i] = f2bf(src[i]);
}

// ---------------- bf16 MFMA GEMM, C = A * B^T (both [rows x K] row-major) ----
// MODE 0: +bias, relu, -> bf16      (MLP layer 1)
// MODE 1: +bias        -> bf16      (MLP layer 2)
// MODE 2: *1/16, clamp, exp -> half (scores -> E)
template<int MODE>
__global__ __launch_bounds__(256, 2)
void k_gemm_bt(const unsigned short* __restrict__ A,
               const unsigned short* __restrict__ Bt,
               void* __restrict__ Out,
               const float* __restrict__ bias,
               int K, long aBatch, long bBatch, long oBatch, int ostride)
{
  __shared__ __align__(16) unsigned short lA[128 * 32];
  __shared__ __align__(16) unsigned short lB[128 * 32];
  const int tid  = threadIdx.x;
  const int lane = tid & 63;
  const int w    = tid >> 6;
  const int wm   = (w >> 1) * 64;
  const int wn   = (w & 1) * 64;
  const long bz  = blockIdx.z;
  const unsigned short* Ab = A  + bz * aBatch + (long)blockIdx.y * 128 * K;
  const unsigned short* Bb = Bt + bz * bBatch + (long)blockIdx.x * 128 * K;

  floatx4 acc[4][4];
  #pragma unroll
  for (int i = 0; i < 4; i++)
    #pragma unroll
    for (int j = 0; j < 4; j++) acc[i][j] = (floatx4){0.f, 0.f, 0.f, 0.f};

  for (int kt = 0; kt < K; kt += 32) {
    __syncthreads();
    #pragma unroll
    for (int s0 = 0; s0 < 512; s0 += 256) {
      int s = s0 + tid;
      int row = s >> 2, part = s & 3;
      ((uint4*)lA)[s] = *(const uint4*)(Ab + (long)row * K + kt + part * 8);
      ((uint4*)lB)[s] = *(const uint4*)(Bb + (long)row * K + kt + part * 8);
    }
    __syncthreads();
    const int kq = (lane >> 4) * 8;   // k sub-offset within BK=32
    const int rl = lane & 15;         // row within 16x16 tile (A: m, B: n)
    short8 af[4], bf[4];
    #pragma unroll
    for (int t = 0; t < 4; t++) {
      af[t] = *(const short8*)(lA + (wm + t * 16 + rl) * 32 + kq);
      bf[t] = *(const short8*)(lB + (wn + t * 16 + rl) * 32 + kq);
    }
    #pragma unroll
    for (int i = 0; i < 4; i++)
      #pragma unroll
      for (int j = 0; j < 4; j++)
        acc[i][j] = __builtin_amdgcn_mfma_f32_16x16x32_bf16(af[i], bf[j], acc[i][j], 0, 0, 0);
  }

  // epilogue — C/D layout: col = lane&15, row = (lane>>4)*4 + reg  [m89/m91 verified]
  const int cl = lane & 15, qd = lane >> 4;
  #pragma unroll
  for (int i = 0; i < 4; i++)
    #pragma unroll
    for (int j = 0; j < 4; j++) {
      const int col = blockIdx.x * 128 + wn + j * 16 + cl;
      const float bcol = (MODE == 2) ? 0.f : bias[col];
      #pragma unroll
      for (int r = 0; r < 4; r++) {
        const long row = (long)blockIdx.y * 128 + wm + i * 16 + qd * 4 + r;
        float v = acc[i][j][r];
        if (MODE == 0) {
          v += bcol; v = v > 0.f ? v : 0.f;
          ((unsigned short*)Out)[bz * oBatch + row * ostride + col] = f2bf(v);
        } else if (MODE == 1) {
          v += bcol;
          ((unsigned short*)Out)[bz * oBatch + row * ostride + col] = f2bf(v);
        } else {
          v *= 0.0625f;                       // 1/sqrt(256)
          v = fminf(fmaxf(v, -15.f), 11.f);   // keep exp(v) inside half range
          ((__half*)Out)[bz * oBatch + row * ostride + col] = __float2half(__expf(v));
        }
      }
    }
}

// ---------------- fill dustbin row/col + zero padding of E -------------------
__global__ void k_fill(__half* __restrict__ E, const float* __restrict__ alphaPtr) {
  const float ea = __expf(*alphaPtr);
  const int idx = blockIdx.x * blockDim.x + threadIdx.x;
  const int n1 = NB * NQ * 16;  // rows 0..2047, cols 2048..2063
  if (idx < n1) {
    int b = idx / (NQ * 16);
    int rr = idx - b * NQ * 16;
    int i = rr >> 4;
    int j = 2048 + (rr & 15);
    E[((long)b * M1 + i) * STR + j] = (j == 2048) ? __float2half(ea) : __float2half(0.f);
  } else {
    int k = idx - n1;             // dustbin row: NB * STR entries
    if (k < NB * STR) {
      int b = k / STR;
      int j = k - b * STR;
      E[((long)b * M1 + 2048) * STR + j] = (j <= 2048) ? __float2half(ea) : __float2half(0.f);
    }
  }
}

// ---------------- init ev = 1, zero barrier counters -------------------------
__global__ void k_init(float* __restrict__ v, int n, unsigned* __restrict__ bar) {
  int i = blockIdx.x * blockDim.x + threadIdx.x;
  if (i < n) v[i] = 1.0f;
  if (i < 2048) bar[i] = 0u;
}

// ---------------- persistent cooperative Sinkhorn ----------------------------
// barrier layout (uint idx): leaf l at l*64 (256B apart), root at 1024, gen at 1088
__device__ __forceinline__ void grid_bar(unsigned* bar, int wg, int tid, unsigned phase) {
  __syncthreads();
  if (tid == 0) {
    unsigned* leaf = bar + (wg & (NLEAF - 1)) * 64;
    unsigned* root = bar + 1024;
    unsigned* gen  = bar + 1088;
    unsigned old = __hip_atomic_fetch_add(leaf, 1u, __ATOMIC_ACQ_REL, __HIP_MEMORY_SCOPE_AGENT);
    if (old == phase * (NWG / NLEAF) - 1u) {
      unsigned r = __hip_atomic_fetch_add(root, 1u, __ATOMIC_ACQ_REL, __HIP_MEMORY_SCOPE_AGENT);
      if (r == phase * NLEAF - 1u)
        __hip_atomic_store(gen, phase, __ATOMIC_RELEASE, __HIP_MEMORY_SCOPE_AGENT);
    }
    while (__hip_atomic_load(gen, __ATOMIC_ACQUIRE, __HIP_MEMORY_SCOPE_AGENT) < phase)
      __builtin_amdgcn_s_sleep(1);
  }
  __syncthreads();
}

__device__ __forceinline__ float dot8(uint4 hv, float4 w0, float4 w1) {
  const __half2* hp = (const __half2*)&hv;
  float2 f0 = __half22float2(hp[0]);
  float2 f1 = __half22float2(hp[1]);
  float2 f2 = __half22float2(hp[2]);
  float2 f3 = __half22float2(hp[3]);
  return f0.x * w0.x + f0.y * w0.y + f1.x * w0.z + f1.y * w0.w
       + f2.x * w1.x + f2.y * w1.y + f3.x * w1.z + f3.y * w1.w;
}

__device__ __forceinline__ float wave_sum(float s) {
  #pragma unroll
  for (int o = 32; o; o >>= 1) s += __shfl_xor(s, o);
  return s;
}

// one half-sweep: vout = marginal / (Mat . vin); WG wg owns rows
// (wg&63)*32 .. +31 of batch wg>>6 (2 rows per wave), last WG of batch adds row 2048
__device__ void half_sweep(const __half* __restrict__ Mat,
                           const float* __restrict__ vin,
                           float* __restrict__ vout,
                           int wg, int tid) {
  const int wave = tid >> 6;            // 0..15
  const int lane = tid & 63;
  const int b    = wg >> 6;             // batch
  const int lr0  = (wg & 63) * 32 + wave * 2;
  const float* wb = vin + b * STR;
  const __half* R0 = Mat + ((long)b * M1 + lr0) * STR;

  float acc0 = 0.f, acc1 = 0.f;
  #pragma unroll
  for (int jc = 0; jc < 4; jc++) {
    const int j = jc * 512 + lane * 8;
    float4 w0 = *(const float4*)(wb + j);
    float4 w1 = *(const float4*)(wb + j + 4);
    uint4 h0 = *(const uint4*)(R0 + j);
    uint4 h1 = *(const uint4*)(R0 + STR + j);
    acc0 += dot8(h0, w0, w1);
    acc1 += dot8(h1, w0, w1);
  }
  acc0 = wave_sum(acc0);
  acc1 = wave_sum(acc1);
  if (lane == 0) {
    const float wdust = wb[2048];
    float s0 = acc0 + __half2float(R0[2048]) * wdust;
    float s1 = acc1 + __half2float(R0[STR + 2048]) * wdust;
    vout[b * STR + lr0]     = (1.f / 4096.f) / s0;   // rows < 2048 always here
    vout[b * STR + lr0 + 1] = (1.f / 4096.f) / s1;
  }

  // dustbin row 2048 (one wave per batch)
  if ((wg & 63) == 63 && wave == 15) {
    const __half* R = Mat + ((long)b * M1 + 2048) * STR;
    float a = 0.f;
    #pragma unroll
    for (int jc = 0; jc < 4; jc++) {
      const int j = jc * 512 + lane * 8;
      float4 w0 = *(const float4*)(wb + j);
      float4 w1 = *(const float4*)(wb + j + 4);
      uint4 h = *(const uint4*)(R + j);
      a += dot8(h, w0, w1);
    }
    a = wave_sum(a);
    if (lane == 0) {
      float s = a + __half2float(R[2048]) * wb[2048];
      vout[b * STR + 2048] = 0.5f / s;
    }
  }
}

__global__ __launch_bounds__(1024, 1)
void k_sink(const __half* __restrict__ E, const __half* __restrict__ ET,
            float* __restrict__ eu, float* __restrict__ ev,
            unsigned* __restrict__ bar) {
  const int wg = blockIdx.x, tid = threadIdx.x;
  unsigned phase = 0;
  for (int it = 0; it < SINK_ITERS; ++it) {
    half_sweep(E, ev, eu, wg, tid);
    grid_bar(bar, wg, tid, ++phase);
    half_sweep(ET, eu, ev, wg, tid);
    grid_bar(bar, wg, tid, ++phase);
  }
}

// ---------------- finalize: out = E * eu * ev * 4096 -------------------------
__global__ void k_final(const __half* __restrict__ E, const float* __restrict__ eu,
                        const float* __restrict__ ev, float* __restrict__ out) {
  const int wv = blockIdx.x;      // NB * M1 rows
  const int b = wv / M1;
  const int i = wv - b * M1;
  const __half* R = E + ((long)b * M1 + i) * STR;
  const float ui = eu[b * STR + i] * 4096.f;   // * exp(-norm)
  const float* evb = ev + b * STR;
  float* orow = out + ((long)b * M1 + i) * M1;
  for (int j = threadIdx.x; j < M1; j += blockDim.x)
    orow[j] = __half2float(R[j]) * ui * evb[j];
}

// ---------------- launch -----------------------------------------------------
extern "C" void kernel_launch(void* const* d_in, const int* in_sizes, int n_in,
                              void* d_out, int out_size, void* d_ws, size_t ws_size,
                              hipStream_t stream) {
  const float* x_lc  = (const float*)d_in[0];
  const float* x_te  = (const float*)d_in[1];
  const float* W1_lc = (const float*)d_in[2];
  const float* b1_lc = (const float*)d_in[3];
  const float* W2_lc = (const float*)d_in[4];
  const float* b2_lc = (const float*)d_in[5];
  const float* W1_te = (const float*)d_in[6];
  const float* b1_te = (const float*)d_in[7];
  const float* W2_te = (const float*)d_in[8];
  const float* b2_te = (const float*)d_in[9];
  const float* alpha = (const float*)d_in[10];

  char* ws = (char*)d_ws;
  unsigned short* Xlc = (unsigned short*)(ws + 0);          //  4 MB
  unsigned short* Xte = (unsigned short*)(ws + 4194304);    //  4 MB
  unsigned short* Wb  = (unsigned short*)(ws + 8388608);    //  0.5 MB
  unsigned short* H   = (unsigned short*)(ws + 8912896);    //  4 MB
  unsigned short* F1  = (unsigned short*)(ws + 13107200);   //  4 MB
  unsigned short* F2  = (unsigned short*)(ws + 17301504);   //  4 MB
  __half* E  = (__half*)(ws + 21495808);                    // 33.83 MB
  __half* ET = (__half*)(ws + 55328896);                    // 33.83 MB
  float* eu  = (float*)(ws + 89161984);                     // 4 x 2064 f32
  float* ev  = (float*)(ws + 89195008);                     // 4 x 2064 f32
  unsigned* bar = (unsigned*)(ws + 89228032);               // 8 KB barrier state

  const int NX = NB * NQ * DD;   // 2097152
  const int NW = DD * DD;        // 65536

  k_cvt<<<(NX + 255) / 256, 256, 0, stream>>>(x_lc, Xlc, NX);
  k_cvt<<<(NX + 255) / 256, 256, 0, stream>>>(x_te, Xte, NX);
  k_cvt<<<(NW + 255) / 256, 256, 0, stream>>>(W1_lc, Wb,           NW);
  k_cvt<<<(NW + 255) / 256, 256, 0, stream>>>(W2_lc, Wb + 65536,   NW);
  k_cvt<<<(NW + 255) / 256, 256, 0, stream>>>(W1_te, Wb + 131072,  NW);
  k_cvt<<<(NW + 255) / 256, 256, 0, stream>>>(W2_te, Wb + 196608,  NW);

  // MLPs (rows flattened over batch: M = 8192, N = 256, K = 256)
  k_gemm_bt<0><<<dim3(2, 64, 1), 256, 0, stream>>>(Xlc, Wb,          H,  b1_lc, DD, 0, 0, 0, DD);
  k_gemm_bt<1><<<dim3(2, 64, 1), 256, 0, stream>>>(H,   Wb + 65536,  F1, b2_lc, DD, 0, 0, 0, DD);
  k_gemm_bt<0><<<dim3(2, 64, 1), 256, 0, stream>>>(Xte, Wb + 131072, H,  b1_te, DD, 0, 0, 0, DD);
  k_gemm_bt<1><<<dim3(2, 64, 1), 256, 0, stream>>>(H,   Wb + 196608, F2, b2_te, DD, 0, 0, 0, DD);

  // scores -> E = exp(S) and ET = exp(S^T), per batch
  const long ab = (long)NQ * DD;        // 524288
  const long ob = (long)M1 * STR;       // 4229136
  k_gemm_bt<2><<<dim3(16, 16, NB), 256, 0, stream>>>(F1, F2, E,  nullptr, DD, ab, ab, ob, STR);
  k_gemm_bt<2><<<dim3(16, 16, NB), 256, 0, stream>>>(F2, F1, ET, nullptr, DD, ab, ab, ob, STR);

  // dustbin row/col + padding
  const int nfill = NB * NQ * 16 + NB * STR;  // 139328
  k_fill<<<(nfill + 255) / 256, 256, 0, stream>>>(E, alpha);
  k_fill<<<(nfill + 255) / 256, 256, 0, stream>>>(ET, alpha);

  // ev = 1, barrier = 0
  k_init<<<(NB * STR + 255) / 256, 256, 0, stream>>>(ev, NB * STR, bar);

  // persistent cooperative Sinkhorn: 100 iterations, grid barrier between half-sweeps
  {
    void* args[] = { (void*)&E, (void*)&ET, (void*)&eu, (void*)&ev, (void*)&bar };
    hipLaunchCooperativeKernel((const void*)k_sink, dim3(NWG), dim3(1024), args, 0, stream);
  }

  // out = E * eu * ev * (m+n)
  k_final<<<NB * M1, 256, 0, stream>>>(E, eu, ev, (float*)d_out);
}

// Round 4
// 1893.006 us; speedup vs baseline: 2.8323x; 2.8323x over previous
//
#include <hip/hip_runtime.h>
#include <hip/hip_fp16.h>

// Problem constants
#define NQ   2048      // N_LC == N_TE
#define NB   4         // batch
#define DD   256       // feature dim
#define M1   2049      // NQ + dustbin
#define STR  2064      // padded row stride (halfs for E, floats for u/v)
#define SINK_ITERS 100
#define NWG  512       // cooperative workgroups (2 per CU)
#define TPB  512       // threads per WG (8 waves)
#define NLEAF 16       // barrier fan-in leaves (32 arrivals each)

typedef __attribute__((ext_vector_type(8))) short short8;
typedef __attribute__((ext_vector_type(4))) float floatx4;

__device__ __forceinline__ unsigned short f2bf(float f) {
  unsigned u = __float_as_uint(f);
  u += 0x7FFF + ((u >> 16) & 1);   // round-to-nearest-even
  return (unsigned short)(u >> 16);
}

// ---------------- fp32 -> bf16 convert ----------------
__global__ void k_cvt(const float* __restrict__ src, unsigned short* __restrict__ dst, int n) {
  int i = blockIdx.x * blockDim.x + threadIdx.x;
  if (i < n) dst[i] = f2bf(src[i]);
}

// ---------------- bf16 MFMA GEMM, C = A * B^T (both [rows x K] row-major) ----
// MODE 0: +bias, relu, -> bf16      (MLP layer 1)
// MODE 1: +bias        -> bf16      (MLP layer 2)
// MODE 2: *1/16, clamp, exp -> half (scores -> E)
template<int MODE>
__global__ __launch_bounds__(256, 2)
void k_gemm_bt(const unsigned short* __restrict__ A,
               const unsigned short* __restrict__ Bt,
               void* __restrict__ Out,
               const float* __restrict__ bias,
               int K, long aBatch, long bBatch, long oBatch, int ostride)
{
  __shared__ __align__(16) unsigned short lA[128 * 32];
  __shared__ __align__(16) unsigned short lB[128 * 32];
  const int tid  = threadIdx.x;
  const int lane = tid & 63;
  const int w    = tid >> 6;
  const int wm   = (w >> 1) * 64;
  const int wn   = (w & 1) * 64;
  const long bz  = blockIdx.z;
  const unsigned short* Ab = A  + bz * aBatch + (long)blockIdx.y * 128 * K;
  const unsigned short* Bb = Bt + bz * bBatch + (long)blockIdx.x * 128 * K;

  floatx4 acc[4][4];
  #pragma unroll
  for (int i = 0; i < 4; i++)
    #pragma unroll
    for (int j = 0; j < 4; j++) acc[i][j] = (floatx4){0.f, 0.f, 0.f, 0.f};

  for (int kt = 0; kt < K; kt += 32) {
    __syncthreads();
    #pragma unroll
    for (int s0 = 0; s0 < 512; s0 += 256) {
      int s = s0 + tid;
      int row = s >> 2, part = s & 3;
      ((uint4*)lA)[s] = *(const uint4*)(Ab + (long)row * K + kt + part * 8);
      ((uint4*)lB)[s] = *(const uint4*)(Bb + (long)row * K + kt + part * 8);
    }
    __syncthreads();
    const int kq = (lane >> 4) * 8;
    const int rl = lane & 15;
    short8 af[4], bf[4];
    #pragma unroll
    for (int t = 0; t < 4; t++) {
      af[t] = *(const short8*)(lA + (wm + t * 16 + rl) * 32 + kq);
      bf[t] = *(const short8*)(lB + (wn + t * 16 + rl) * 32 + kq);
    }
    #pragma unroll
    for (int i = 0; i < 4; i++)
      #pragma unroll
      for (int j = 0; j < 4; j++)
        acc[i][j] = __builtin_amdgcn_mfma_f32_16x16x32_bf16(af[i], bf[j], acc[i][j], 0, 0, 0);
  }

  // epilogue — C/D layout: col = lane&15, row = (lane>>4)*4 + reg
  const int cl = lane & 15, qd = lane >> 4;
  #pragma unroll
  for (int i = 0; i < 4; i++)
    #pragma unroll
    for (int j = 0; j < 4; j++) {
      const int col = blockIdx.x * 128 + wn + j * 16 + cl;
      const float bcol = (MODE == 2) ? 0.f : bias[col];
      #pragma unroll
      for (int r = 0; r < 4; r++) {
        const long row = (long)blockIdx.y * 128 + wm + i * 16 + qd * 4 + r;
        float v = acc[i][j][r];
        if (MODE == 0) {
          v += bcol; v = v > 0.f ? v : 0.f;
          ((unsigned short*)Out)[bz * oBatch + row * ostride + col] = f2bf(v);
        } else if (MODE == 1) {
          v += bcol;
          ((unsigned short*)Out)[bz * oBatch + row * ostride + col] = f2bf(v);
        } else {
          v *= 0.0625f;                       // 1/sqrt(256)
          v = fminf(fmaxf(v, -15.f), 11.f);   // keep exp(v) inside half range
          ((__half*)Out)[bz * oBatch + row * ostride + col] = __float2half(__expf(v));
        }
      }
    }
}

// ---------------- fill dustbin row/col + zero padding of E -------------------
__global__ void k_fill(__half* __restrict__ E, const float* __restrict__ alphaPtr) {
  const float ea = __expf(*alphaPtr);
  const int idx = blockIdx.x * blockDim.x + threadIdx.x;
  const int n1 = NB * NQ * 16;  // rows 0..2047, cols 2048..2063
  if (idx < n1) {
    int b = idx / (NQ * 16);
    int rr = idx - b * NQ * 16;
    int i = rr >> 4;
    int j = 2048 + (rr & 15);
    E[((long)b * M1 + i) * STR + j] = (j == 2048) ? __float2half(ea) : __float2half(0.f);
  } else {
    int k = idx - n1;             // dustbin row: NB * STR entries
    if (k < NB * STR) {
      int b = k / STR;
      int j = k - b * STR;
      E[((long)b * M1 + 2048) * STR + j] = (j <= 2048) ? __float2half(ea) : __float2half(0.f);
    }
  }
}

// ---------------- init ev = 1, zero barrier state ----------------------------
__global__ void k_init(float* __restrict__ v, int n, unsigned* __restrict__ bar) {
  int i = blockIdx.x * blockDim.x + threadIdx.x;
  if (i < n) v[i] = 1.0f;
  if (i < 2048) bar[i] = 0u;
}

// ---------------- persistent cooperative Sinkhorn ----------------------------
// ALL atomics RELAXED at agent scope -> plain sc1 global ops, NO buffer_inv.
// Ordering: __syncthreads drains vmcnt before s_barrier (compiler-guaranteed),
// so all waves' sc1 stores are LLC-visible before tid0 bumps the leaf counter.
__device__ __forceinline__ void st_agent(float* p, float v) {
  __hip_atomic_store(p, v, __ATOMIC_RELAXED, __HIP_MEMORY_SCOPE_AGENT);
}
__device__ __forceinline__ float ld_agent(const float* p) {
  return __hip_atomic_load(p, __ATOMIC_RELAXED, __HIP_MEMORY_SCOPE_AGENT);
}

// barrier layout (uint idx): leaf l at l*64 (256B apart), root at 1024, gen at 1088
__device__ __forceinline__ void grid_bar(unsigned* bar, int wg, int tid, unsigned phase) {
  __syncthreads();   // drains vmcnt(0): this wave's & WG's stores are at LLC
  if (tid == 0) {
    unsigned* leaf = bar + (wg & (NLEAF - 1)) * 64;
    unsigned* root = bar + 1024;
    unsigned* gen  = bar + 1088;
    unsigned old = __hip_atomic_fetch_add(leaf, 1u, __ATOMIC_RELAXED, __HIP_MEMORY_SCOPE_AGENT);
    if (old == phase * (NWG / NLEAF) - 1u) {
      unsigned r = __hip_atomic_fetch_add(root, 1u, __ATOMIC_RELAXED, __HIP_MEMORY_SCOPE_AGENT);
      if (r == phase * NLEAF - 1u)
        __hip_atomic_store(gen, phase, __ATOMIC_RELAXED, __HIP_MEMORY_SCOPE_AGENT);
    }
    while (__hip_atomic_load(gen, __ATOMIC_RELAXED, __HIP_MEMORY_SCOPE_AGENT) < phase)
      __builtin_amdgcn_s_sleep(2);
  }
  __syncthreads();
}

__device__ __forceinline__ float dot8(uint4 hv, float4 w0, float4 w1) {
  const __half2* hp = (const __half2*)&hv;
  float2 f0 = __half22float2(hp[0]);
  float2 f1 = __half22float2(hp[1]);
  float2 f2 = __half22float2(hp[2]);
  float2 f3 = __half22float2(hp[3]);
  return f0.x * w0.x + f0.y * w0.y + f1.x * w0.z + f1.y * w0.w
       + f2.x * w1.x + f2.y * w1.y + f3.x * w1.z + f3.y * w1.w;
}

__device__ __forceinline__ float wave_sum(float s) {
  #pragma unroll
  for (int o = 32; o; o >>= 1) s += __shfl_xor(s, o);
  return s;
}

// 512 WGs: 128 per batch; WG g owns rows g*16..g*16+15 (2 rows per wave).
// Dustbin row is analytic: u_dust = mu_dust / (ea * sum(vin[0..2048])),
// computed by wave 0 of g==0 from the LDS-staged vector (E dustbin row == ea).
__global__ __launch_bounds__(TPB, 4)
void k_sink(const __half* __restrict__ E, const __half* __restrict__ ET,
            float* __restrict__ eu, float* __restrict__ ev,
            const float* __restrict__ alphaPtr, unsigned* __restrict__ bar)
{
  __shared__ __align__(16) float sv[STR];
  const int tid  = threadIdx.x;
  const int wg   = blockIdx.x;
  const int b    = wg >> 7;          // batch
  const int g    = wg & 127;
  const int wv   = tid >> 6;         // 0..7
  const int lane = tid & 63;
  const int r0   = (g * 8 + wv) * 2; // rows r0, r0+1 in [0, 2048)
  const float ea = __expf(alphaPtr[0]);
  const __half* Er  = E  + ((long)b * M1 + r0) * STR;
  const __half* ETr = ET + ((long)b * M1 + r0) * STR;
  float* ub = eu + b * STR;
  float* vb = ev + b * STR;

  unsigned phase = 0;
  for (int it = 0; it < 2 * SINK_ITERS; ++it) {
    const bool fwd = (it & 1) == 0;
    const __half* R   = fwd ? Er : ETr;
    const float* vin  = fwd ? vb : ub;
    float*       vout = fwd ? ub : vb;

    // stage vin -> LDS (sc1 loads: fresh from LLC, no cache invalidation)
    for (int j = tid; j < STR; j += TPB) sv[j] = ld_agent(vin + j);
    __syncthreads();

    float a0 = 0.f, a1 = 0.f;
    #pragma unroll
    for (int jc = 0; jc < 4; jc++) {
      const int j = jc * 512 + lane * 8;
      uint4 h0 = *(const uint4*)(R + j);          // plain cached loads (read-only)
      uint4 h1 = *(const uint4*)(R + STR + j);
      float4 w0 = *(const float4*)(sv + j);
      float4 w1 = *(const float4*)(sv + j + 4);
      a0 += dot8(h0, w0, w1);
      a1 += dot8(h1, w0, w1);
    }
    a0 = wave_sum(a0);
    a1 = wave_sum(a1);
    if (lane == 0) {
      const float wd = ea * sv[2048];             // dustbin column (value == ea)
      st_agent(vout + r0,     (1.f / 4096.f) / (a0 + wd));
      st_agent(vout + r0 + 1, (1.f / 4096.f) / (a1 + wd));
    }

    // dustbin row (one wave per batch, overlaps with row work of other waves)
    if (g == 0 && wv == 0) {
      float s = 0.f;
      #pragma unroll
      for (int jc = 0; jc < 4; jc++) {
        const int j = jc * 512 + lane * 8;
        float4 x0 = *(const float4*)(sv + j);
        float4 x1 = *(const float4*)(sv + j + 4);
        s += x0.x + x0.y + x0.z + x0.w + x1.x + x1.y + x1.z + x1.w;
      }
      s = wave_sum(s);
      if (lane == 0) st_agent(vout + 2048, 0.5f / (ea * (s + sv[2048])));
    }

    grid_bar(bar, wg, tid, ++phase);
  }
}

// ---------------- finalize: out = E * eu * ev * 4096 -------------------------
__global__ void k_final(const __half* __restrict__ E, const float* __restrict__ eu,
                        const float* __restrict__ ev, float* __restrict__ out) {
  const int wv = blockIdx.x;      // NB * M1 rows
  const int b = wv / M1;
  const int i = wv - b * M1;
  const __half* R = E + ((long)b * M1 + i) * STR;
  const float ui = eu[b * STR + i] * 4096.f;   // * exp(-norm)
  const float* evb = ev + b * STR;
  float* orow = out + ((long)b * M1 + i) * M1;
  for (int j = threadIdx.x; j < M1; j += blockDim.x)
    orow[j] = __half2float(R[j]) * ui * evb[j];
}

// ---------------- launch -----------------------------------------------------
extern "C" void kernel_launch(void* const* d_in, const int* in_sizes, int n_in,
                              void* d_out, int out_size, void* d_ws, size_t ws_size,
                              hipStream_t stream) {
  const float* x_lc  = (const float*)d_in[0];
  const float* x_te  = (const float*)d_in[1];
  const float* W1_lc = (const float*)d_in[2];
  const float* b1_lc = (const float*)d_in[3];
  const float* W2_lc = (const float*)d_in[4];
  const float* b2_lc = (const float*)d_in[5];
  const float* W1_te = (const float*)d_in[6];
  const float* b1_te = (const float*)d_in[7];
  const float* W2_te = (const float*)d_in[8];
  const float* b2_te = (const float*)d_in[9];
  const float* alpha = (const float*)d_in[10];

  char* ws = (char*)d_ws;
  unsigned short* Xlc = (unsigned short*)(ws + 0);          //  4 MB
  unsigned short* Xte = (unsigned short*)(ws + 4194304);    //  4 MB
  unsigned short* Wb  = (unsigned short*)(ws + 8388608);    //  0.5 MB
  unsigned short* H   = (unsigned short*)(ws + 8912896);    //  4 MB
  unsigned short* F1  = (unsigned short*)(ws + 13107200);   //  4 MB
  unsigned short* F2  = (unsigned short*)(ws + 17301504);   //  4 MB
  __half* E  = (__half*)(ws + 21495808);                    // 33.83 MB
  __half* ET = (__half*)(ws + 55328896);                    // 33.83 MB
  float* eu  = (float*)(ws + 89161984);                     // 4 x 2064 f32
  float* ev  = (float*)(ws + 89195008);                     // 4 x 2064 f32
  unsigned* bar = (unsigned*)(ws + 89228032);               // 8 KB barrier state

  const int NX = NB * NQ * DD;   // 2097152
  const int NW = DD * DD;        // 65536

  k_cvt<<<(NX + 255) / 256, 256, 0, stream>>>(x_lc, Xlc, NX);
  k_cvt<<<(NX + 255) / 256, 256, 0, stream>>>(x_te, Xte, NX);
  k_cvt<<<(NW + 255) / 256, 256, 0, stream>>>(W1_lc, Wb,           NW);
  k_cvt<<<(NW + 255) / 256, 256, 0, stream>>>(W2_lc, Wb + 65536,   NW);
  k_cvt<<<(NW + 255) / 256, 256, 0, stream>>>(W1_te, Wb + 131072,  NW);
  k_cvt<<<(NW + 255) / 256, 256, 0, stream>>>(W2_te, Wb + 196608,  NW);

  // MLPs (rows flattened over batch: M = 8192, N = 256, K = 256)
  k_gemm_bt<0><<<dim3(2, 64, 1), 256, 0, stream>>>(Xlc, Wb,          H,  b1_lc, DD, 0, 0, 0, DD);
  k_gemm_bt<1><<<dim3(2, 64, 1), 256, 0, stream>>>(H,   Wb + 65536,  F1, b2_lc, DD, 0, 0, 0, DD);
  k_gemm_bt<0><<<dim3(2, 64, 1), 256, 0, stream>>>(Xte, Wb + 131072, H,  b1_te, DD, 0, 0, 0, DD);
  k_gemm_bt<1><<<dim3(2, 64, 1), 256, 0, stream>>>(H,   Wb + 196608, F2, b2_te, DD, 0, 0, 0, DD);

  // scores -> E = exp(S) and ET = exp(S^T), per batch (fp16)
  const long ab = (long)NQ * DD;        // 524288
  const long ob = (long)M1 * STR;       // 4229136
  k_gemm_bt<2><<<dim3(16, 16, NB), 256, 0, stream>>>(F1, F2, E,  nullptr, DD, ab, ab, ob, STR);
  k_gemm_bt<2><<<dim3(16, 16, NB), 256, 0, stream>>>(F2, F1, ET, nullptr, DD, ab, ab, ob, STR);

  // dustbin row/col + padding
  const int nfill = NB * NQ * 16 + NB * STR;  // 139328
  k_fill<<<(nfill + 255) / 256, 256, 0, stream>>>(E, alpha);
  k_fill<<<(nfill + 255) / 256, 256, 0, stream>>>(ET, alpha);

  // ev = 1, barrier = 0
  k_init<<<(NB * STR + 255) / 256, 256, 0, stream>>>(ev, NB * STR, bar);

  // persistent cooperative Sinkhorn: 100 iterations, relaxed-atomic grid barrier
  {
    void* args[] = { (void*)&E, (void*)&ET, (void*)&eu, (void*)&ev,
                     (void*)&alpha, (void*)&bar };
    hipLaunchCooperativeKernel((const void*)k_sink, dim3(NWG), dim3(TPB), args, 0, stream);
  }

  // out = E * eu * ev * (m+n)
  k_final<<<NB * M1, 256, 0, stream>>>(E, eu, ev, (float*)d_out);
}

// Round 7
// 1049.597 us; speedup vs baseline: 5.1082x; 1.8036x over previous
//
#include <hip/hip_runtime.h>
#include <hip/hip_fp16.h>

// Problem constants
#define NQ   2048      // N_LC == N_TE
#define NB   4         // batch
#define DD   256       // feature dim
#define M1   2049      // NQ + dustbin
#define STR  2064      // padded row stride (fp16 elems for E, bytes for E8, floats for u/v)
#define SINK_ITERS 100
#define PNWG 256       // persistent WGs (64 per batch) — <= guaranteed co-residency (512)
#define PTPB 1024      // 16 waves per WG

typedef __attribute__((ext_vector_type(8))) short short8;
typedef __attribute__((ext_vector_type(4))) float floatx4;
typedef __attribute__((ext_vector_type(2))) float floatx2;

__device__ __forceinline__ unsigned short f2bf(float f) {
  unsigned u = __float_as_uint(f);
  u += 0x7FFF + ((u >> 16) & 1);   // round-to-nearest-even
  return (unsigned short)(u >> 16);
}

// fp32 -> fp8 e5m2 (OCP): e5m2 == top byte of IEEE half, RN
__device__ __forceinline__ unsigned char f2fp8(float f) {
  unsigned short u = __half_as_ushort(__float2half(f));
  return (unsigned char)((u + 0x7F + ((u >> 8) & 1)) >> 8);
}

// swizzled LDS index: pad 1 float per 16 -> lane stride 17 floats (2-way = free)
__device__ __forceinline__ int IDX(int j) { return j + (j >> 4); }

// ---------------- fp32 -> bf16 convert ----------------
__global__ void k_cvt(const float* __restrict__ src, unsigned short* __restrict__ dst, int n) {
  int i = blockIdx.x * blockDim.x + threadIdx.x;
  if (i < n) dst[i] = f2bf(src[i]);
}

// ---------------- bf16 MFMA GEMM, C = A * B^T (both [rows x K] row-major) ----
// MODE 0: +bias, relu -> bf16          (MLP layer 1)
// MODE 1: +bias       -> bf16          (MLP layer 2)
// MODE 2: *1/16, clamp, exp -> fp16 AND fp8 e5m2   (scores -> E, E8)
// MODE 3: *1/16, clamp, exp -> fp8 e5m2 only       (scores -> ET8)
template<int MODE>
__global__ __launch_bounds__(256, 2)
void k_gemm_bt(const unsigned short* __restrict__ A,
               const unsigned short* __restrict__ Bt,
               void* __restrict__ Out, void* __restrict__ Out8,
               const float* __restrict__ bias,
               int K, long aBatch, long bBatch, long oBatch, int ostride)
{
  __shared__ __align__(16) unsigned short lA[128 * 32];
  __shared__ __align__(16) unsigned short lB[128 * 32];
  const int tid  = threadIdx.x;
  const int lane = tid & 63;
  const int w    = tid >> 6;
  const int wm   = (w >> 1) * 64;
  const int wn   = (w & 1) * 64;
  const long bz  = blockIdx.z;
  const unsigned short* Ab = A  + bz * aBatch + (long)blockIdx.y * 128 * K;
  const unsigned short* Bb = Bt + bz * bBatch + (long)blockIdx.x * 128 * K;

  floatx4 acc[4][4];
  #pragma unroll
  for (int i = 0; i < 4; i++)
    #pragma unroll
    for (int j = 0; j < 4; j++) acc[i][j] = (floatx4){0.f, 0.f, 0.f, 0.f};

  for (int kt = 0; kt < K; kt += 32) {
    __syncthreads();
    #pragma unroll
    for (int s0 = 0; s0 < 512; s0 += 256) {
      int s = s0 + tid;
      int row = s >> 2, part = s & 3;
      ((uint4*)lA)[s] = *(const uint4*)(Ab + (long)row * K + kt + part * 8);
      ((uint4*)lB)[s] = *(const uint4*)(Bb + (long)row * K + kt + part * 8);
    }
    __syncthreads();
    const int kq = (lane >> 4) * 8;
    const int rl = lane & 15;
    short8 af[4], bf[4];
    #pragma unroll
    for (int t = 0; t < 4; t++) {
      af[t] = *(const short8*)(lA + (wm + t * 16 + rl) * 32 + kq);
      bf[t] = *(const short8*)(lB + (wn + t * 16 + rl) * 32 + kq);
    }
    #pragma unroll
    for (int i = 0; i < 4; i++)
      #pragma unroll
      for (int j = 0; j < 4; j++)
        acc[i][j] = __builtin_amdgcn_mfma_f32_16x16x32_bf16(af[i], bf[j], acc[i][j], 0, 0, 0);
  }

  // epilogue — C/D layout: col = lane&15, row = (lane>>4)*4 + reg
  const int cl = lane & 15, qd = lane >> 4;
  #pragma unroll
  for (int i = 0; i < 4; i++)
    #pragma unroll
    for (int j = 0; j < 4; j++) {
      const int col = blockIdx.x * 128 + wn + j * 16 + cl;
      const float bcol = (MODE >= 2) ? 0.f : bias[col];
      #pragma unroll
      for (int r = 0; r < 4; r++) {
        const long row = (long)blockIdx.y * 128 + wm + i * 16 + qd * 4 + r;
        float v = acc[i][j][r];
        if (MODE == 0) {
          v += bcol; v = v > 0.f ? v : 0.f;
          ((unsigned short*)Out)[bz * oBatch + row * ostride + col] = f2bf(v);
        } else if (MODE == 1) {
          v += bcol;
          ((unsigned short*)Out)[bz * oBatch + row * ostride + col] = f2bf(v);
        } else {
          v *= 0.0625f;                       // 1/sqrt(256)
          v = fminf(fmaxf(v, -15.f), 10.9f);  // e^10.9 = 54k < e5m2 max 57344
          float e = __expf(v);
          const long idx = bz * oBatch + row * ostride + col;
          if (MODE == 2) ((__half*)Out)[idx] = __float2half(e);
          ((unsigned char*)Out8)[idx] = f2fp8(e);
        }
      }
    }
}

// ---------------- fill dustbin row/col + zero padding of fp16 E --------------
__global__ void k_fill(__half* __restrict__ E, const float* __restrict__ alphaPtr) {
  const float ea = __expf(*alphaPtr);
  const int idx = blockIdx.x * blockDim.x + threadIdx.x;
  const int n1 = NB * NQ * 16;  // rows 0..2047, cols 2048..2063
  if (idx < n1) {
    int b = idx / (NQ * 16);
    int rr = idx - b * NQ * 16;
    int i = rr >> 4;
    int j = 2048 + (rr & 15);
    E[((long)b * M1 + i) * STR + j] = (j == 2048) ? __float2half(ea) : __float2half(0.f);
  } else {
    int k = idx - n1;             // dustbin row: NB * STR entries
    if (k < NB * STR) {
      int b = k / STR;
      int j = k - b * STR;
      E[((long)b * M1 + 2048) * STR + j] = (j <= 2048) ? __float2half(ea) : __float2half(0.f);
    }
  }
}

// ---------------- init ev = 1, zero barrier state ----------------------------
__global__ void k_init(float* __restrict__ v, int n, unsigned* __restrict__ bar) {
  int i = blockIdx.x * blockDim.x + threadIdx.x;
  if (i < n) v[i] = 1.0f;
  if (i < 2048) bar[i] = 0u;   // 4 batches x 512 uints of barrier state
}

// ---------------- agent-scope relaxed helpers (NO cache invalidates) ---------
__device__ __forceinline__ void st_agent(float* p, float v) {
  __hip_atomic_store(p, v, __ATOMIC_RELAXED, __HIP_MEMORY_SCOPE_AGENT);
}
__device__ __forceinline__ float ld_agent(const float* p) {
  return __hip_atomic_load(p, __ATOMIC_RELAXED, __HIP_MEMORY_SCOPE_AGENT);
}

__device__ __forceinline__ float wave_sum(float s) {
  #pragma unroll
  for (int o = 32; o; o >>= 1) s += __shfl_xor(s, o);
  return s;
}

// dot of 16 fp8(e5m2) values with 16 fp32 weights at wp[0..15]
__device__ __forceinline__ float dot16f8(uint4 hv, const float* wp) {
  const unsigned* u = (const unsigned*)&hv;
  float s = 0.f;
#if __has_builtin(__builtin_amdgcn_cvt_pk_f32_bf8)
  #pragma unroll
  for (int q = 0; q < 4; q++) {
    floatx2 lo = __builtin_amdgcn_cvt_pk_f32_bf8((int)u[q], false);
    floatx2 hi = __builtin_amdgcn_cvt_pk_f32_bf8((int)u[q], true);
    s += lo.x * wp[q * 4 + 0] + lo.y * wp[q * 4 + 1]
       + hi.x * wp[q * 4 + 2] + hi.y * wp[q * 4 + 3];
  }
#else
  const unsigned char* p = (const unsigned char*)&hv;
  #pragma unroll
  for (int t = 0; t < 16; t++) {
    unsigned short h = (unsigned short)p[t] << 8;
    s += __half2float(*reinterpret_cast<__half*>(&h)) * wp[t];
  }
#endif
  return s;
}

// ---------------- persistent Sinkhorn, plain launch (NOT cooperative) --------
// Grid 256 WGs x 1024 thr. Co-residency guaranteed: __launch_bounds__(1024,4)
// => >=16 waves/CU => >=2 WGs/CU capacity (512) >= grid (256); barriers cannot
// deadlock. 64 WGs per batch; per-batch 8-leaf barrier tree (independent sync
// domains). Fixed 100 iterations — identical work every call (tripwire-safe).
// u/v traffic via agent-scope relaxed atomics (sc1, LLC-coherent, NO L2
// invalidates — the R2 lesson). E8/ET8 read-only via plain cached loads.
__global__ __launch_bounds__(PTPB, 4)
void k_sink(const unsigned char* __restrict__ E8, const unsigned char* __restrict__ ET8,
            float* __restrict__ eu, float* __restrict__ ev,
            const float* __restrict__ alphaPtr, unsigned* __restrict__ bar)
{
  __shared__ __align__(16) float sv[2200];   // swizzled vector (2064 + pads)
  const int tid  = threadIdx.x;
  const int wg   = blockIdx.x;
  const int b    = wg >> 6;          // batch 0..3
  const int g    = wg & 63;          // group within batch
  const int wv   = tid >> 6;         // wave 0..15
  const int lane = tid & 63;
  const int r0   = (g * 16 + wv) * 2;   // rows r0, r0+1 in [0, 2048)
  const float ea = __expf(alphaPtr[0]);
  const unsigned char* E8r  = E8  + ((long)b * M1 + r0) * STR;
  const unsigned char* ET8r = ET8 + ((long)b * M1 + r0) * STR;
  float* ub = eu + b * STR;
  float* vb = ev + b * STR;
  // per-batch barrier state: 512 uints; leaves 128 B apart
  unsigned* bb   = bar + b * 512;
  unsigned* leaf = bb + (g & 7) * 32;    // 8 leaves x 8 arrivals
  unsigned* root = bb + 8 * 32;
  unsigned* gen  = bb + 9 * 32;
  const bool dustwave = (g == 63) && (wv == 15);

  unsigned phase = 0;
  for (int it = 0; it < 2 * SINK_ITERS; ++it) {
    const unsigned char* R = (it & 1) ? ET8r : E8r;
    const float* vin = (it & 1) ? ub : vb;
    float*      vout = (it & 1) ? vb : ub;

    // stage vin -> swizzled LDS (sc1: fresh from LLC; 3 rounds, tid0 gets 2048)
    for (int j = tid; j < M1; j += PTPB) sv[IDX(j)] = ld_agent(vin + j);
    __syncthreads();

    // two fp8 rows per wave, 16 bytes per lane per 1024-chunk
    uint4 h0c0 = *(const uint4*)(R + lane * 16);
    uint4 h0c1 = *(const uint4*)(R + 1024 + lane * 16);
    uint4 h1c0 = *(const uint4*)(R + STR + lane * 16);
    uint4 h1c1 = *(const uint4*)(R + STR + 1024 + lane * 16);
    const float* w0 = sv + lane * 17;          // IDX(lane*16)
    const float* w1 = sv + 1088 + lane * 17;   // IDX(1024 + lane*16)
    float a0 = dot16f8(h0c0, w0) + dot16f8(h0c1, w1);
    float a1 = dot16f8(h1c0, w0) + dot16f8(h1c1, w1);
    a0 = wave_sum(a0);
    a1 = wave_sum(a1);
    if (lane == 0) {
      const float wd = ea * sv[IDX(2048)];     // dustbin column (value == ea)
      st_agent(vout + r0,     (1.f / 4096.f) / (a0 + wd));
      st_agent(vout + r0 + 1, (1.f / 4096.f) / (a1 + wd));
    }

    // dustbin row analytic: vout[2048] = 0.5 / (ea * sum(vin))
    if (dustwave) {
      float s = 0.f;
      #pragma unroll
      for (int t = 0; t < 16; t++) s += w0[t] + w1[t];
      s = wave_sum(s);
      if (lane == 0) st_agent(vout + 2048, 0.5f / (ea * (s + sv[IDX(2048)])));
    }

    // ---- per-batch grid barrier (relaxed tree, no cache maintenance) ----
    ++phase;
    __syncthreads();   // drains vmcnt: this WG's sc1 stores are at LLC
    if (tid == 0) {
      unsigned old = __hip_atomic_fetch_add(leaf, 1u, __ATOMIC_RELAXED, __HIP_MEMORY_SCOPE_AGENT);
      if (old == phase * 8u - 1u) {
        unsigned r = __hip_atomic_fetch_add(root, 1u, __ATOMIC_RELAXED, __HIP_MEMORY_SCOPE_AGENT);
        if (r == phase * 8u - 1u)
          __hip_atomic_store(gen, phase, __ATOMIC_RELAXED, __HIP_MEMORY_SCOPE_AGENT);
      }
      while (__hip_atomic_load(gen, __ATOMIC_RELAXED, __HIP_MEMORY_SCOPE_AGENT) < phase)
        __builtin_amdgcn_s_sleep(1);
    }
    __syncthreads();
  }
}

// ---------------- finalize: out = E * eu * ev * 4096 (fp16 E) ----------------
__global__ void k_final(const __half* __restrict__ E, const float* __restrict__ eu,
                        const float* __restrict__ ev, float* __restrict__ out) {
  const int wv = blockIdx.x;      // NB * M1 rows
  const int b = wv / M1;
  const int i = wv - b * M1;
  const __half* R = E + ((long)b * M1 + i) * STR;
  const float ui = eu[b * STR + i] * 4096.f;   // * exp(-norm)
  const float* evb = ev + b * STR;
  float* orow = out + ((long)b * M1 + i) * M1;
  for (int j = threadIdx.x; j < M1; j += blockDim.x)
    orow[j] = __half2float(R[j]) * ui * evb[j];
}

// ---------------- launch -----------------------------------------------------
extern "C" void kernel_launch(void* const* d_in, const int* in_sizes, int n_in,
                              void* d_out, int out_size, void* d_ws, size_t ws_size,
                              hipStream_t stream) {
  const float* x_lc  = (const float*)d_in[0];
  const float* x_te  = (const float*)d_in[1];
  const float* W1_lc = (const float*)d_in[2];
  const float* b1_lc = (const float*)d_in[3];
  const float* W2_lc = (const float*)d_in[4];
  const float* b2_lc = (const float*)d_in[5];
  const float* W1_te = (const float*)d_in[6];
  const float* b1_te = (const float*)d_in[7];
  const float* W2_te = (const float*)d_in[8];
  const float* b2_te = (const float*)d_in[9];
  const float* alpha = (const float*)d_in[10];

  char* ws = (char*)d_ws;
  unsigned short* Xlc = (unsigned short*)(ws + 0);          //  4 MB
  unsigned short* Xte = (unsigned short*)(ws + 4194304);    //  4 MB
  unsigned short* Wb  = (unsigned short*)(ws + 8388608);    //  0.5 MB
  unsigned short* H   = (unsigned short*)(ws + 8912896);    //  4 MB
  unsigned short* F1  = (unsigned short*)(ws + 13107200);   //  4 MB
  unsigned short* F2  = (unsigned short*)(ws + 17301504);   //  4 MB
  __half* E  = (__half*)(ws + 21495808);                    // 33.83 MB fp16 (final)
  unsigned char* E8  = (unsigned char*)(ws + 55328896);     // 16.92 MB fp8 (sweep)
  unsigned char* ET8 = (unsigned char*)(ws + 72245440);     // 16.92 MB fp8 (sweep)
  float* eu  = (float*)(ws + 89161984);                     // 4 x 2064 f32
  float* ev  = (float*)(ws + 89195008);                     // 4 x 2064 f32
  unsigned* bar = (unsigned*)(ws + 89228032);               // 8 KB barrier state

  const int NX = NB * NQ * DD;   // 2097152
  const int NW = DD * DD;        // 65536

  k_cvt<<<(NX + 255) / 256, 256, 0, stream>>>(x_lc, Xlc, NX);
  k_cvt<<<(NX + 255) / 256, 256, 0, stream>>>(x_te, Xte, NX);
  k_cvt<<<(NW + 255) / 256, 256, 0, stream>>>(W1_lc, Wb,           NW);
  k_cvt<<<(NW + 255) / 256, 256, 0, stream>>>(W2_lc, Wb + 65536,   NW);
  k_cvt<<<(NW + 255) / 256, 256, 0, stream>>>(W1_te, Wb + 131072,  NW);
  k_cvt<<<(NW + 255) / 256, 256, 0, stream>>>(W2_te, Wb + 196608,  NW);

  // MLPs (rows flattened over batch: M = 8192, N = 256, K = 256)
  k_gemm_bt<0><<<dim3(2, 64, 1), 256, 0, stream>>>(Xlc, Wb,          H,  nullptr, b1_lc, DD, 0, 0, 0, DD);
  k_gemm_bt<1><<<dim3(2, 64, 1), 256, 0, stream>>>(H,   Wb + 65536,  F1, nullptr, b2_lc, DD, 0, 0, 0, DD);
  k_gemm_bt<0><<<dim3(2, 64, 1), 256, 0, stream>>>(Xte, Wb + 131072, H,  nullptr, b1_te, DD, 0, 0, 0, DD);
  k_gemm_bt<1><<<dim3(2, 64, 1), 256, 0, stream>>>(H,   Wb + 196608, F2, nullptr, b2_te, DD, 0, 0, 0, DD);

  // scores -> E (fp16+fp8) and ET (fp8 only), per batch
  const long ab = (long)NQ * DD;        // 524288
  const long ob = (long)M1 * STR;       // 4229136 (elems for fp16, bytes for fp8)
  k_gemm_bt<2><<<dim3(16, 16, NB), 256, 0, stream>>>(F1, F2, E,  E8,  nullptr, DD, ab, ab, ob, STR);
  k_gemm_bt<3><<<dim3(16, 16, NB), 256, 0, stream>>>(F2, F1, nullptr, ET8, nullptr, DD, ab, ab, ob, STR);

  // dustbin row/col + padding (fp16 E only; fp8 dustbin handled analytically)
  const int nfill = NB * NQ * 16 + NB * STR;  // 139328
  k_fill<<<(nfill + 255) / 256, 256, 0, stream>>>(E, alpha);

  // ev = 1, barrier = 0
  k_init<<<(NB * STR + 255) / 256, 256, 0, stream>>>(ev, NB * STR, bar);

  // persistent Sinkhorn: ONE plain launch, fixed 100 iterations
  k_sink<<<PNWG, PTPB, 0, stream>>>(E8, ET8, eu, ev, alpha, bar);

  // out = E * eu * ev * (m+n)
  k_final<<<NB * M1, 256, 0, stream>>>(E, eu, ev, (float*)d_out);
}